// Round 2
// baseline (13937.152 us; speedup 1.0000x reference)
//
#include <hip/hip_runtime.h>
#include <hip/hip_bf16.h>
#include <math.h>

#define NEG_ATT 0.2f
#define NEG_ACT 0.01f

__device__ __forceinline__ float lrelu(float v, float s) { return v >= 0.f ? v : s * v; }

// -------------------- K1: h1 = x @ W1 (+ per-head attention dots) --------------------
// block 256 = 8 head-groups (tid>>5) x 32 nodes (tid&31). W1 (128x128, 64KB) staged in LDS.
// Within a wave: lanes 0-31 share one hg, 32-63 the next -> LDS reads are 2-address
// broadcast (conflict-free).
__global__ __launch_bounds__(256) void k_gemm1(
    const float* __restrict__ x, const float* __restrict__ W,
    const float* __restrict__ a_src, const float* __restrict__ a_dst,
    float* __restrict__ h1, float* __restrict__ as1, float* __restrict__ ad1, int N)
{
    __shared__ float Wl[128 * 128];
    const int tid = threadIdx.x;
    {
        float4* Wl4 = (float4*)Wl;
        const float4* W4 = (const float4*)W;
        #pragma unroll
        for (int i = 0; i < 16; ++i) Wl4[tid + i * 256] = W4[tid + i * 256];
    }
    __syncthreads();

    const int nl = tid & 31, hg = tid >> 5;
    int n = blockIdx.x * 32 + nl;
    if (n >= N) n = N - 1;  // N divisible by 32 in this problem; clamp for safety

    const float4* xrow = (const float4*)(x + (size_t)n * 128);
    float acc[16];
    #pragma unroll
    for (int j = 0; j < 16; ++j) acc[j] = 0.f;

    for (int k4 = 0; k4 < 32; ++k4) {
        float4 xv4 = xrow[k4];
        float xs[4] = {xv4.x, xv4.y, xv4.z, xv4.w};
        #pragma unroll
        for (int kk = 0; kk < 4; ++kk) {
            const float4* wr = (const float4*)(Wl + (k4 * 4 + kk) * 128 + hg * 16);
            float4 w0 = wr[0], w1 = wr[1], w2 = wr[2], w3 = wr[3];
            float xv = xs[kk];
            acc[0]  = fmaf(xv, w0.x, acc[0]);  acc[1]  = fmaf(xv, w0.y, acc[1]);
            acc[2]  = fmaf(xv, w0.z, acc[2]);  acc[3]  = fmaf(xv, w0.w, acc[3]);
            acc[4]  = fmaf(xv, w1.x, acc[4]);  acc[5]  = fmaf(xv, w1.y, acc[5]);
            acc[6]  = fmaf(xv, w1.z, acc[6]);  acc[7]  = fmaf(xv, w1.w, acc[7]);
            acc[8]  = fmaf(xv, w2.x, acc[8]);  acc[9]  = fmaf(xv, w2.y, acc[9]);
            acc[10] = fmaf(xv, w2.z, acc[10]); acc[11] = fmaf(xv, w2.w, acc[11]);
            acc[12] = fmaf(xv, w3.x, acc[12]); acc[13] = fmaf(xv, w3.y, acc[13]);
            acc[14] = fmaf(xv, w3.z, acc[14]); acc[15] = fmaf(xv, w3.w, acc[15]);
        }
    }

    float s_src = 0.f, s_dst = 0.f;
    const float* av = a_src + hg * 16;
    const float* bv = a_dst + hg * 16;
    #pragma unroll
    for (int j = 0; j < 16; ++j) {
        s_src = fmaf(acc[j], av[j], s_src);
        s_dst = fmaf(acc[j], bv[j], s_dst);
    }

    float4* h4 = (float4*)(h1 + (size_t)n * 128 + hg * 16);
    h4[0] = make_float4(acc[0],  acc[1],  acc[2],  acc[3]);
    h4[1] = make_float4(acc[4],  acc[5],  acc[6],  acc[7]);
    h4[2] = make_float4(acc[8],  acc[9],  acc[10], acc[11]);
    h4[3] = make_float4(acc[12], acc[13], acc[14], acc[15]);
    as1[n * 8 + hg] = s_src;
    ad1[n * 8 + hg] = s_dst;
}

// -------------------- K2: layer-1 edge pass (denom + weighted scatter) --------------------
// One thread per (edge, head). Softmax division deferred to node level, so a single pass
// accumulates both denom1[d,h] and num1[d,h,:] = sum_e exp(e)*h1[s,h,:].
__global__ __launch_bounds__(256) void k_edge1(
    const int* __restrict__ src, const int* __restrict__ dst,
    const float* __restrict__ as1, const float* __restrict__ ad1,
    const float* __restrict__ h1,
    float* __restrict__ denom1, float* __restrict__ num1, int E, int Etot)
{
    int idx = blockIdx.x * 256 + threadIdx.x;
    int e = idx >> 3, h = idx & 7;
    if (e >= Etot) return;
    int s, d;
    if (e < E) { s = src[e]; d = dst[e]; } else { s = e - E; d = s; }  // self-loops appended
    float w = expf(lrelu(as1[s * 8 + h] + ad1[d * 8 + h], NEG_ATT));
    atomicAdd(denom1 + d * 8 + h, w);
    const float4* hs = (const float4*)(h1 + (size_t)s * 128 + h * 16);
    float* o = num1 + (size_t)d * 128 + h * 16;
    #pragma unroll
    for (int q = 0; q < 4; ++q) {
        float4 v = hs[q];
        atomicAdd(o + q * 4 + 0, w * v.x);
        atomicAdd(o + q * 4 + 1, w * v.y);
        atomicAdd(o + q * 4 + 2, w * v.z);
        atomicAdd(o + q * 4 + 3, w * v.w);
    }
}

// -------------------- K4: layer-2 input transform + small GEMM + attention dots ----------
// block 256 = 16 nodes x 16 outputs. x2 = leaky(num1/denom1 + b1, 0.01) staged in padded LDS.
__global__ __launch_bounds__(256) void k_layer2(
    const float* __restrict__ num1, const float* __restrict__ denom1,
    const float* __restrict__ b1, const float* __restrict__ W2,
    const float* __restrict__ a2_src, const float* __restrict__ a2_dst,
    float* __restrict__ h2, float* __restrict__ as2, float* __restrict__ ad2, int N)
{
    __shared__ float x2s[16 * 132];   // +4 pad: conflict-free broadcast reads
    __shared__ float W2s[128 * 16];
    const int tid = threadIdx.x;
    {
        float4* d4 = (float4*)W2s;
        const float4* s4 = (const float4*)W2;
        d4[tid] = s4[tid];
        d4[tid + 256] = s4[tid + 256];
    }
    const int node0 = blockIdx.x * 16;
    #pragma unroll
    for (int i = 0; i < 2; ++i) {
        int i4 = tid + i * 256;          // float4 index within the 16x128 tile
        int gf = i4 * 4;
        int nl = gf >> 7, f = gf & 127, hh = f >> 4;
        int nn = node0 + nl; if (nn >= N) nn = N - 1;
        float4 v = *(const float4*)(num1 + (size_t)nn * 128 + f);
        float inv = 1.f / denom1[nn * 8 + hh];
        float4 bb = ((const float4*)b1)[i4 & 31];
        float4 r;
        r.x = lrelu(fmaf(v.x, inv, bb.x), NEG_ACT);
        r.y = lrelu(fmaf(v.y, inv, bb.y), NEG_ACT);
        r.z = lrelu(fmaf(v.z, inv, bb.z), NEG_ACT);
        r.w = lrelu(fmaf(v.w, inv, bb.w), NEG_ACT);
        *(float4*)(x2s + nl * 132 + f) = r;
    }
    __syncthreads();

    const int nl = tid >> 4, j = tid & 15;
    const int n = node0 + nl;
    float acc = 0.f;
    const float* xr = x2s + nl * 132;
    #pragma unroll 8
    for (int k = 0; k < 128; ++k) acc = fmaf(xr[k], W2s[k * 16 + j], acc);

    if (n < N) h2[(size_t)n * 16 + j] = acc;
    float ps = acc * a2_src[j];
    float pd = acc * a2_dst[j];
    #pragma unroll
    for (int m = 8; m >= 1; m >>= 1) {
        ps += __shfl_xor(ps, m, 16);
        pd += __shfl_xor(pd, m, 16);
    }
    if (j == 0 && n < N) { as2[n] = ps; ad2[n] = pd; }
}

// -------------------- K5: layer-2 edge pass (H=1) --------------------
__global__ __launch_bounds__(256) void k_edge2(
    const int* __restrict__ src, const int* __restrict__ dst,
    const float* __restrict__ as2, const float* __restrict__ ad2,
    const float* __restrict__ h2, float* __restrict__ denom2, float* __restrict__ out2,
    int E, int Etot)
{
    int e = blockIdx.x * 256 + threadIdx.x;
    if (e >= Etot) return;
    int s, d;
    if (e < E) { s = src[e]; d = dst[e]; } else { s = e - E; d = s; }
    float w = expf(lrelu(as2[s] + ad2[d], NEG_ATT));
    atomicAdd(denom2 + d, w);
    const float4* hs = (const float4*)(h2 + (size_t)s * 16);
    float* o = out2 + (size_t)d * 16;
    #pragma unroll
    for (int q = 0; q < 4; ++q) {
        float4 v = hs[q];
        atomicAdd(o + q * 4 + 0, w * v.x);
        atomicAdd(o + q * 4 + 1, w * v.y);
        atomicAdd(o + q * 4 + 2, w * v.z);
        atomicAdd(o + q * 4 + 3, w * v.w);
    }
}

// -------------------- K7: finalize (divide, +b2, row softmax) in-place on d_out ----------
__global__ __launch_bounds__(256) void k_softmax(
    float* __restrict__ out, const float* __restrict__ denom2, const float* __restrict__ b2, int N)
{
    int n = blockIdx.x * 256 + threadIdx.x;
    if (n >= N) return;
    float inv = 1.f / denom2[n];
    float t[16];
    const float4* r4 = (const float4*)(out + (size_t)n * 16);
    #pragma unroll
    for (int q = 0; q < 4; ++q) {
        float4 v = r4[q];
        t[q * 4 + 0] = fmaf(v.x, inv, b2[q * 4 + 0]);
        t[q * 4 + 1] = fmaf(v.y, inv, b2[q * 4 + 1]);
        t[q * 4 + 2] = fmaf(v.z, inv, b2[q * 4 + 2]);
        t[q * 4 + 3] = fmaf(v.w, inv, b2[q * 4 + 3]);
    }
    float m = t[0];
    #pragma unroll
    for (int j = 1; j < 16; ++j) m = fmaxf(m, t[j]);
    float ssum = 0.f;
    #pragma unroll
    for (int j = 0; j < 16; ++j) { t[j] = expf(t[j] - m); ssum += t[j]; }
    float r = 1.f / ssum;
    float4* w4 = (float4*)(out + (size_t)n * 16);
    #pragma unroll
    for (int q = 0; q < 4; ++q)
        w4[q] = make_float4(t[q * 4 + 0] * r, t[q * 4 + 1] * r, t[q * 4 + 2] * r, t[q * 4 + 3] * r);
}

extern "C" void kernel_launch(void* const* d_in, const int* in_sizes, int n_in,
                              void* d_out, int out_size, void* d_ws, size_t ws_size,
                              hipStream_t stream)
{
    const float* x   = (const float*)d_in[0];
    const int*   ei  = (const int*)d_in[1];
    const float* W1  = (const float*)d_in[2];
    const float* a1s = (const float*)d_in[3];
    const float* a1d = (const float*)d_in[4];
    const float* b1  = (const float*)d_in[5];
    const float* W2  = (const float*)d_in[6];
    const float* a2s = (const float*)d_in[7];
    const float* a2d = (const float*)d_in[8];
    const float* b2  = (const float*)d_in[9];

    const int N = in_sizes[0] / 128;
    const int E = in_sizes[1] / 2;
    const int Etot = E + N;
    const int* srcp = ei;
    const int* dstp = ei + E;

    // workspace layout (floats): ~120 MB total
    float* p = (float*)d_ws;
    float* h1     = p; p += (size_t)N * 128;
    float* as1    = p; p += (size_t)N * 8;
    float* ad1    = p; p += (size_t)N * 8;
    float* denom1 = p; p += (size_t)N * 8;
    float* num1   = p; p += (size_t)N * 128;
    float* h2     = p; p += (size_t)N * 16;
    float* as2    = p; p += N;
    float* ad2    = p; p += N;
    float* denom2 = p; p += N;
    float* logits = (float*)d_out;

    hipMemsetAsync(denom1, 0, (size_t)N * 8 * sizeof(float), stream);
    hipMemsetAsync(num1,   0, (size_t)N * 128 * sizeof(float), stream);
    hipMemsetAsync(denom2, 0, (size_t)N * sizeof(float), stream);
    hipMemsetAsync(d_out,  0, (size_t)N * 16 * sizeof(float), stream);

    k_gemm1<<<(N + 31) / 32, 256, 0, stream>>>(x, W1, a1s, a1d, h1, as1, ad1, N);
    k_edge1<<<((Etot * 8) + 255) / 256, 256, 0, stream>>>(srcp, dstp, as1, ad1, h1, denom1, num1, E, Etot);
    k_layer2<<<(N + 15) / 16, 256, 0, stream>>>(num1, denom1, b1, W2, a2s, a2d, h2, as2, ad2, N);
    k_edge2<<<(Etot + 255) / 256, 256, 0, stream>>>(srcp, dstp, as2, ad2, h2, denom2, logits, E, Etot);
    k_softmax<<<(N + 255) / 256, 256, 0, stream>>>(logits, denom2, b2, N);
}

// Round 4
// 742.608 us; speedup vs baseline: 18.7678x; 18.7678x over previous
//
#include <hip/hip_runtime.h>
#include <hip/hip_bf16.h>
#include <math.h>

#define NEG_ATT 0.2f
#define NEG_ACT 0.01f

__device__ __forceinline__ float lrelu(float v, float s) { return v >= 0.f ? v : s * v; }

// ==================== CSR build: histogram -> scan -> scatter ====================
__global__ __launch_bounds__(256) void k_hist(
    const int* __restrict__ dst, int* __restrict__ counts, int E, int Etot)
{
    int e = blockIdx.x * 256 + threadIdx.x;
    if (e >= Etot) return;
    int d = (e < E) ? dst[e] : e - E;   // self-loops appended as edges [E, E+N)
    atomicAdd(&counts[d], 1);
}

// Single-block exclusive prefix sum (1024 threads, shfl-based wave scan).
// Writes exclusive prefix into cursor[]; k_scatter advances cursor to segment ends.
__global__ __launch_bounds__(1024) void k_scan(
    const int* __restrict__ counts, int* __restrict__ cursor, int N)
{
    __shared__ int wsum[16];
    __shared__ int carry_s;
    const int tid = threadIdx.x;
    const int lane = tid & 63, w = tid >> 6;
    if (tid == 0) carry_s = 0;
    __syncthreads();
    for (int base = 0; base < N; base += 1024) {
        int i = base + tid;
        int v = (i < N) ? counts[i] : 0;
        int incl = v;
        #pragma unroll
        for (int s = 1; s < 64; s <<= 1) {
            int t = __shfl_up(incl, s, 64);
            if (lane >= s) incl += t;
        }
        if (lane == 63) wsum[w] = incl;
        __syncthreads();
        int woff = 0;
        #pragma unroll
        for (int k = 0; k < 16; ++k) woff += (k < w) ? wsum[k] : 0;
        int carry = carry_s;
        if (i < N) cursor[i] = carry + woff + incl - v;   // exclusive
        __syncthreads();
        if (tid == 1023) carry_s = carry + woff + incl;
        __syncthreads();
    }
}

__global__ __launch_bounds__(256) void k_scatter(
    const int* __restrict__ src, const int* __restrict__ dst,
    int* __restrict__ cursor, int* __restrict__ csr, int E, int Etot)
{
    int e = blockIdx.x * 256 + threadIdx.x;
    if (e >= Etot) return;
    int s, d;
    if (e < E) { s = src[e]; d = dst[e]; } else { s = e - E; d = s; }
    int pos = atomicAdd(&cursor[d], 1);
    csr[pos] = s;
}

// ==================== K1: h1 = x @ W1 (+ per-head attention dots) ====================
// block 256 = 8 head-groups x 32 nodes. W1 (64KB) in LDS; 2-address broadcast reads.
__global__ __launch_bounds__(256) void k_gemm1(
    const float* __restrict__ x, const float* __restrict__ W,
    const float* __restrict__ a_src, const float* __restrict__ a_dst,
    float* __restrict__ h1, float* __restrict__ as1, float* __restrict__ ad1, int N)
{
    __shared__ float Wl[128 * 128];
    const int tid = threadIdx.x;
    {
        float4* Wl4 = (float4*)Wl;
        const float4* W4 = (const float4*)W;
        #pragma unroll
        for (int i = 0; i < 16; ++i) Wl4[tid + i * 256] = W4[tid + i * 256];
    }
    __syncthreads();

    const int nl = tid & 31, hg = tid >> 5;
    int n = blockIdx.x * 32 + nl;
    if (n >= N) n = N - 1;

    const float4* xrow = (const float4*)(x + (size_t)n * 128);
    float acc[16];
    #pragma unroll
    for (int j = 0; j < 16; ++j) acc[j] = 0.f;

    for (int k4 = 0; k4 < 32; ++k4) {
        float4 xv4 = xrow[k4];
        float xs[4] = {xv4.x, xv4.y, xv4.z, xv4.w};
        #pragma unroll
        for (int kk = 0; kk < 4; ++kk) {
            const float4* wr = (const float4*)(Wl + (k4 * 4 + kk) * 128 + hg * 16);
            float4 w0 = wr[0], w1 = wr[1], w2 = wr[2], w3 = wr[3];
            float xv = xs[kk];
            acc[0]  = fmaf(xv, w0.x, acc[0]);  acc[1]  = fmaf(xv, w0.y, acc[1]);
            acc[2]  = fmaf(xv, w0.z, acc[2]);  acc[3]  = fmaf(xv, w0.w, acc[3]);
            acc[4]  = fmaf(xv, w1.x, acc[4]);  acc[5]  = fmaf(xv, w1.y, acc[5]);
            acc[6]  = fmaf(xv, w1.z, acc[6]);  acc[7]  = fmaf(xv, w1.w, acc[7]);
            acc[8]  = fmaf(xv, w2.x, acc[8]);  acc[9]  = fmaf(xv, w2.y, acc[9]);
            acc[10] = fmaf(xv, w2.z, acc[10]); acc[11] = fmaf(xv, w2.w, acc[11]);
            acc[12] = fmaf(xv, w3.x, acc[12]); acc[13] = fmaf(xv, w3.y, acc[13]);
            acc[14] = fmaf(xv, w3.z, acc[14]); acc[15] = fmaf(xv, w3.w, acc[15]);
        }
    }

    float s_src = 0.f, s_dst = 0.f;
    const float* av = a_src + hg * 16;
    const float* bv = a_dst + hg * 16;
    #pragma unroll
    for (int j = 0; j < 16; ++j) {
        s_src = fmaf(acc[j], av[j], s_src);
        s_dst = fmaf(acc[j], bv[j], s_dst);
    }

    float4* h4 = (float4*)(h1 + (size_t)n * 128 + hg * 16);
    h4[0] = make_float4(acc[0],  acc[1],  acc[2],  acc[3]);
    h4[1] = make_float4(acc[4],  acc[5],  acc[6],  acc[7]);
    h4[2] = make_float4(acc[8],  acc[9],  acc[10], acc[11]);
    h4[3] = make_float4(acc[12], acc[13], acc[14], acc[15]);
    as1[n * 8 + hg] = s_src;
    ad1[n * 8 + hg] = s_dst;
}

// ==================== K2: layer-1 gather-aggregate (one wave per dst) ====================
// Fuses: attention weights, weighted sum, softmax-denominator divide, +b1, leaky(0.01).
// Lane owns channels 2*lane, 2*lane+1; head = lane>>3. Writes x2[N,128] directly.
__global__ __launch_bounds__(256) void k_agg1(
    const int* __restrict__ csr, const int* __restrict__ cursor, const int* __restrict__ counts,
    const float* __restrict__ as1, const float* __restrict__ ad1,
    const float* __restrict__ h1, const float* __restrict__ b1,
    float* __restrict__ x2, int N)
{
    const int d = (blockIdx.x * 256 + threadIdx.x) >> 6;   // one wave per destination
    if (d >= N) return;
    const int lane = threadIdx.x & 63;
    const int h = lane >> 3;
    const int deg = counts[d];
    const int start = cursor[d] - deg;   // cursor holds segment END after k_scatter

    const float myad = ad1[d * 8 + h];
    float acc0 = 0.f, acc1 = 0.f, wsum = 0.f;
    for (int j = 0; j < deg; ++j) {
        int s = csr[start + j];
        float wgt = __expf(lrelu(as1[s * 8 + h] + myad, NEG_ATT));
        float2 hv = *(const float2*)(h1 + (size_t)s * 128 + lane * 2);
        acc0 = fmaf(wgt, hv.x, acc0);
        acc1 = fmaf(wgt, hv.y, acc1);
        wsum += wgt;
    }
    float inv = 1.f / wsum;
    float2 bb = *(const float2*)(b1 + lane * 2);
    float2 r;
    r.x = lrelu(fmaf(acc0, inv, bb.x), NEG_ACT);
    r.y = lrelu(fmaf(acc1, inv, bb.y), NEG_ACT);
    *(float2*)(x2 + (size_t)d * 128 + lane * 2) = r;
}

// ==================== K3: h2 = x2 @ W2 (+ scalar attention dots) ====================
__global__ __launch_bounds__(256) void k_layer2(
    const float* __restrict__ x2, const float* __restrict__ W2,
    const float* __restrict__ a2_src, const float* __restrict__ a2_dst,
    float* __restrict__ h2, float* __restrict__ as2, float* __restrict__ ad2, int N)
{
    __shared__ float x2s[16 * 132];   // +4 pad
    __shared__ float W2s[128 * 16];
    const int tid = threadIdx.x;
    {
        float4* d4 = (float4*)W2s;
        const float4* s4 = (const float4*)W2;
        d4[tid] = s4[tid];
        d4[tid + 256] = s4[tid + 256];
    }
    const int node0 = blockIdx.x * 16;
    #pragma unroll
    for (int i = 0; i < 2; ++i) {
        int i4 = tid + i * 256;
        int gf = i4 * 4;
        int nl = gf >> 7, f = gf & 127;
        int nn = node0 + nl; if (nn >= N) nn = N - 1;
        *(float4*)(x2s + nl * 132 + f) = *(const float4*)(x2 + (size_t)nn * 128 + f);
    }
    __syncthreads();

    const int nl = tid >> 4, j = tid & 15;
    const int n = node0 + nl;
    float acc = 0.f;
    const float* xr = x2s + nl * 132;
    #pragma unroll 8
    for (int k = 0; k < 128; ++k) acc = fmaf(xr[k], W2s[k * 16 + j], acc);

    if (n < N) h2[(size_t)n * 16 + j] = acc;
    float ps = acc * a2_src[j];
    float pd = acc * a2_dst[j];
    #pragma unroll
    for (int m = 8; m >= 1; m >>= 1) {
        ps += __shfl_xor(ps, m, 16);
        pd += __shfl_xor(pd, m, 16);
    }
    if (j == 0 && n < N) { as2[n] = ps; ad2[n] = pd; }
}

// ==================== K4: layer-2 gather + bias + final softmax (16 lanes/dst) ==========
__global__ __launch_bounds__(256) void k_agg2(
    const int* __restrict__ csr, const int* __restrict__ cursor, const int* __restrict__ counts,
    const float* __restrict__ as2, const float* __restrict__ ad2,
    const float* __restrict__ h2, const float* __restrict__ b2,
    float* __restrict__ out, int N)
{
    const int d = (blockIdx.x * 256 + threadIdx.x) >> 4;
    if (d >= N) return;
    const int j = threadIdx.x & 15;
    const int deg = counts[d];
    const int start = cursor[d] - deg;

    const float myad = ad2[d];
    float acc = 0.f, wsum = 0.f;
    for (int t = 0; t < deg; ++t) {
        int s = csr[start + t];
        float wgt = __expf(lrelu(as2[s] + myad, NEG_ATT));
        acc = fmaf(wgt, h2[(size_t)s * 16 + j], acc);
        wsum += wgt;
    }
    float logit = acc / wsum + b2[j];
    float m = logit;
    #pragma unroll
    for (int s = 8; s >= 1; s >>= 1) m = fmaxf(m, __shfl_xor(m, s, 16));
    float ex = __expf(logit - m);
    float sum = ex;
    #pragma unroll
    for (int s = 8; s >= 1; s >>= 1) sum += __shfl_xor(sum, s, 16);
    out[(size_t)d * 16 + j] = ex / sum;
}

extern "C" void kernel_launch(void* const* d_in, const int* in_sizes, int n_in,
                              void* d_out, int out_size, void* d_ws, size_t ws_size,
                              hipStream_t stream)
{
    const float* x   = (const float*)d_in[0];
    const int*   ei  = (const int*)d_in[1];
    const float* W1  = (const float*)d_in[2];
    const float* a1s = (const float*)d_in[3];
    const float* a1d = (const float*)d_in[4];
    const float* b1  = (const float*)d_in[5];
    const float* W2  = (const float*)d_in[6];
    const float* a2s = (const float*)d_in[7];
    const float* a2d = (const float*)d_in[8];
    const float* b2  = (const float*)d_in[9];

    const int N = in_sizes[0] / 128;
    const int E = in_sizes[1] / 2;
    const int Etot = E + N;
    const int* srcp = ei;
    const int* dstp = ei + E;

    // workspace layout (~116 MB): h1 region is reused for h2/as2/ad2 after k_agg1.
    float* p = (float*)d_ws;
    float* h1  = p; p += (size_t)N * 128;
    float* as1 = p; p += (size_t)N * 8;
    float* ad1 = p; p += (size_t)N * 8;
    float* x2  = p; p += (size_t)N * 128;
    int* counts = (int*)p; p += N;
    int* cursor = (int*)p; p += N;
    int* csr    = (int*)p; p += Etot;

    float* h2  = h1;               // aliases: h1 dead after k_agg1
    float* as2 = h1 + (size_t)N * 16;
    float* ad2 = h1 + (size_t)N * 17;

    hipMemsetAsync(counts, 0, (size_t)N * sizeof(int), stream);

    k_hist   <<<(Etot + 255) / 256, 256, 0, stream>>>(dstp, counts, E, Etot);
    k_scan   <<<1, 1024, 0, stream>>>(counts, cursor, N);
    k_scatter<<<(Etot + 255) / 256, 256, 0, stream>>>(srcp, dstp, cursor, csr, E, Etot);
    k_gemm1  <<<(N + 31) / 32, 256, 0, stream>>>(x, W1, a1s, a1d, h1, as1, ad1, N);
    k_agg1   <<<(N + 3) / 4, 256, 0, stream>>>(csr, cursor, counts, as1, ad1, h1, b1, x2, N);
    k_layer2 <<<(N + 15) / 16, 256, 0, stream>>>(x2, W2, a2s, a2d, h2, as2, ad2, N);
    k_agg2   <<<(N * 16 + 255) / 256, 256, 0, stream>>>(csr, cursor, counts, as2, ad2, h2, b2, (float*)d_out, N);
}

// Round 6
// 563.462 us; speedup vs baseline: 24.7348x; 1.3179x over previous
//
#include <hip/hip_runtime.h>
#include <hip/hip_bf16.h>
#include <math.h>

#define NEG_ATT 0.2f
#define NEG_ACT 0.01f

__device__ __forceinline__ float lrelu(float v, float s) { return v >= 0.f ? v : s * v; }

// ==================== CSR build ====================
__global__ __launch_bounds__(256) void k_hist(
    const int* __restrict__ dst, int* __restrict__ counts, int E, int Etot)
{
    int e = blockIdx.x * 256 + threadIdx.x;
    if (e >= Etot) return;
    int d = (e < E) ? dst[e] : e - E;   // self-loops appended as edges [E, E+N)
    atomicAdd(&counts[d], 1);
}

// pass 1: per-1024-block sums
__global__ __launch_bounds__(1024) void k_bsum(
    const int* __restrict__ counts, int* __restrict__ bsum, int N)
{
    int i = blockIdx.x * 1024 + threadIdx.x;
    int v = (i < N) ? counts[i] : 0;
    #pragma unroll
    for (int m = 1; m < 64; m <<= 1) v += __shfl_xor(v, m, 64);
    __shared__ int ws[16];
    int lane = threadIdx.x & 63, w = threadIdx.x >> 6;
    if (lane == 0) ws[w] = v;
    __syncthreads();
    if (threadIdx.x == 0) {
        int t = 0;
        #pragma unroll
        for (int k = 0; k < 16; ++k) t += ws[k];
        bsum[blockIdx.x] = t;
    }
}

// generic single-block exclusive scan (used for the ~98 block sums)
__global__ __launch_bounds__(1024) void k_scan(
    const int* __restrict__ in, int* __restrict__ out, int N)
{
    __shared__ int wsum[16];
    __shared__ int carry_s;
    const int tid = threadIdx.x;
    const int lane = tid & 63, w = tid >> 6;
    if (tid == 0) carry_s = 0;
    __syncthreads();
    for (int base = 0; base < N; base += 1024) {
        int i = base + tid;
        int v = (i < N) ? in[i] : 0;
        int incl = v;
        #pragma unroll
        for (int s = 1; s < 64; s <<= 1) {
            int t = __shfl_up(incl, s, 64);
            if (lane >= s) incl += t;
        }
        if (lane == 63) wsum[w] = incl;
        __syncthreads();
        int woff = 0;
        #pragma unroll
        for (int k = 0; k < 16; ++k) woff += (k < w) ? wsum[k] : 0;
        int carry = carry_s;
        if (i < N) out[i] = carry + woff + incl - v;   // exclusive
        __syncthreads();
        if (tid == 1023) carry_s = carry + woff + incl;
        __syncthreads();
    }
}

// pass 3: per-block local exclusive scan + block offset -> cursor
__global__ __launch_bounds__(1024) void k_scanadd(
    const int* __restrict__ counts, const int* __restrict__ boff,
    int* __restrict__ cursor, int N)
{
    const int tid = threadIdx.x;
    const int i = blockIdx.x * 1024 + tid;
    int v = (i < N) ? counts[i] : 0;
    int incl = v;
    const int lane = tid & 63, w = tid >> 6;
    #pragma unroll
    for (int s = 1; s < 64; s <<= 1) {
        int t = __shfl_up(incl, s, 64);
        if (lane >= s) incl += t;
    }
    __shared__ int ws[16];
    if (lane == 63) ws[w] = incl;
    __syncthreads();
    int woff = 0;
    #pragma unroll
    for (int k = 0; k < 16; ++k) woff += (k < w) ? ws[k] : 0;
    if (i < N) cursor[i] = boff[blockIdx.x] + woff + incl - v;
}

__global__ __launch_bounds__(256) void k_scatter(
    const int* __restrict__ src, const int* __restrict__ dst,
    int* __restrict__ cursor, int* __restrict__ csr, int E, int Etot)
{
    int e = blockIdx.x * 256 + threadIdx.x;
    if (e >= Etot) return;
    int s, d;
    if (e < E) { s = src[e]; d = dst[e]; } else { s = e - E; d = s; }
    int pos = atomicAdd(&cursor[d], 1);
    csr[pos] = s;
}

// ==================== K1: h1 = x @ W1 (+ per-head attention dots) ====================
__global__ __launch_bounds__(256) void k_gemm1(
    const float* __restrict__ x, const float* __restrict__ W,
    const float* __restrict__ a_src, const float* __restrict__ a_dst,
    float* __restrict__ h1, float* __restrict__ as1, float* __restrict__ ad1, int N)
{
    __shared__ float Wl[128 * 128];
    const int tid = threadIdx.x;
    {
        float4* Wl4 = (float4*)Wl;
        const float4* W4 = (const float4*)W;
        #pragma unroll
        for (int i = 0; i < 16; ++i) Wl4[tid + i * 256] = W4[tid + i * 256];
    }
    __syncthreads();

    const int nl = tid & 31, hg = tid >> 5;
    int n = blockIdx.x * 32 + nl;
    if (n >= N) n = N - 1;

    const float4* xrow = (const float4*)(x + (size_t)n * 128);
    float acc[16];
    #pragma unroll
    for (int j = 0; j < 16; ++j) acc[j] = 0.f;

    for (int k4 = 0; k4 < 32; ++k4) {
        float4 xv4 = xrow[k4];
        float xs[4] = {xv4.x, xv4.y, xv4.z, xv4.w};
        #pragma unroll
        for (int kk = 0; kk < 4; ++kk) {
            const float4* wr = (const float4*)(Wl + (k4 * 4 + kk) * 128 + hg * 16);
            float4 w0 = wr[0], w1 = wr[1], w2 = wr[2], w3 = wr[3];
            float xv = xs[kk];
            acc[0]  = fmaf(xv, w0.x, acc[0]);  acc[1]  = fmaf(xv, w0.y, acc[1]);
            acc[2]  = fmaf(xv, w0.z, acc[2]);  acc[3]  = fmaf(xv, w0.w, acc[3]);
            acc[4]  = fmaf(xv, w1.x, acc[4]);  acc[5]  = fmaf(xv, w1.y, acc[5]);
            acc[6]  = fmaf(xv, w1.z, acc[6]);  acc[7]  = fmaf(xv, w1.w, acc[7]);
            acc[8]  = fmaf(xv, w2.x, acc[8]);  acc[9]  = fmaf(xv, w2.y, acc[9]);
            acc[10] = fmaf(xv, w2.z, acc[10]); acc[11] = fmaf(xv, w2.w, acc[11]);
            acc[12] = fmaf(xv, w3.x, acc[12]); acc[13] = fmaf(xv, w3.y, acc[13]);
            acc[14] = fmaf(xv, w3.z, acc[14]); acc[15] = fmaf(xv, w3.w, acc[15]);
        }
    }

    float s_src = 0.f, s_dst = 0.f;
    const float* av = a_src + hg * 16;
    const float* bv = a_dst + hg * 16;
    #pragma unroll
    for (int j = 0; j < 16; ++j) {
        s_src = fmaf(acc[j], av[j], s_src);
        s_dst = fmaf(acc[j], bv[j], s_dst);
    }

    float4* h4 = (float4*)(h1 + (size_t)n * 128 + hg * 16);
    h4[0] = make_float4(acc[0],  acc[1],  acc[2],  acc[3]);
    h4[1] = make_float4(acc[4],  acc[5],  acc[6],  acc[7]);
    h4[2] = make_float4(acc[8],  acc[9],  acc[10], acc[11]);
    h4[3] = make_float4(acc[12], acc[13], acc[14], acc[15]);
    as1[n * 8 + hg] = s_src;
    ad1[n * 8 + hg] = s_dst;
}

// ==================== K2: layer-1 gather + fused layer-2 transform ====================
// One wave per dst. Edge loop: csr indices preloaded one-per-lane (shfl broadcast),
// unrolled x4 => ~8 gathers in flight (breaks the dependent-load chain).
// Tail: x2 row (2 ch/lane) -> 128x16 GEMM via per-lane partials + shfl_xor tree;
// writes h2[d,16], as2[d], ad2[d] directly (k_layer2 eliminated).
__global__ __launch_bounds__(256) void k_agg1(
    const int* __restrict__ csr, const int* __restrict__ cursor, const int* __restrict__ counts,
    const float* __restrict__ as1, const float* __restrict__ ad1,
    const float* __restrict__ h1, const float* __restrict__ b1,
    const float* __restrict__ W2, const float* __restrict__ a2_src, const float* __restrict__ a2_dst,
    float* __restrict__ h2, float* __restrict__ as2, float* __restrict__ ad2, int N)
{
    const int d = (blockIdx.x * 256 + threadIdx.x) >> 6;   // one wave per destination
    if (d >= N) return;                                     // wave-uniform; no barriers below
    const int lane = threadIdx.x & 63;
    const int h = lane >> 3;
    const int deg = counts[d];
    const int start = cursor[d] - deg;   // cursor holds segment END after k_scatter

    const float myad = ad1[d * 8 + h];
    float acc0 = 0.f, acc1 = 0.f, wsum = 0.f;

    for (int base = 0; base < deg; base += 64) {
        int cnt = min(deg - base, 64);
        int lidx = lane < cnt ? lane : cnt - 1;
        int sj = csr[start + base + lidx];
        int j = 0;
        for (; j + 4 <= cnt; j += 4) {
            int s0 = __shfl(sj, j);
            int s1 = __shfl(sj, j + 1);
            int s2 = __shfl(sj, j + 2);
            int s3 = __shfl(sj, j + 3);
            float e0 = as1[s0 * 8 + h], e1 = as1[s1 * 8 + h];
            float e2 = as1[s2 * 8 + h], e3 = as1[s3 * 8 + h];
            float2 v0 = *(const float2*)(h1 + (size_t)s0 * 128 + lane * 2);
            float2 v1 = *(const float2*)(h1 + (size_t)s1 * 128 + lane * 2);
            float2 v2 = *(const float2*)(h1 + (size_t)s2 * 128 + lane * 2);
            float2 v3 = *(const float2*)(h1 + (size_t)s3 * 128 + lane * 2);
            float w0 = __expf(lrelu(e0 + myad, NEG_ATT));
            float w1 = __expf(lrelu(e1 + myad, NEG_ATT));
            float w2 = __expf(lrelu(e2 + myad, NEG_ATT));
            float w3 = __expf(lrelu(e3 + myad, NEG_ATT));
            acc0 = fmaf(w0, v0.x, acc0); acc1 = fmaf(w0, v0.y, acc1);
            acc0 = fmaf(w1, v1.x, acc0); acc1 = fmaf(w1, v1.y, acc1);
            acc0 = fmaf(w2, v2.x, acc0); acc1 = fmaf(w2, v2.y, acc1);
            acc0 = fmaf(w3, v3.x, acc0); acc1 = fmaf(w3, v3.y, acc1);
            wsum += w0 + w1 + w2 + w3;
        }
        for (; j < cnt; ++j) {
            int s = __shfl(sj, j);
            float wgt = __expf(lrelu(as1[s * 8 + h] + myad, NEG_ATT));
            float2 hv = *(const float2*)(h1 + (size_t)s * 128 + lane * 2);
            acc0 = fmaf(wgt, hv.x, acc0);
            acc1 = fmaf(wgt, hv.y, acc1);
            wsum += wgt;
        }
    }

    // x2 row elements owned by this lane (channels 2*lane, 2*lane+1)
    float inv = 1.f / wsum;
    float2 bb = *(const float2*)(b1 + lane * 2);
    float xa = lrelu(fmaf(acc0, inv, bb.x), NEG_ACT);
    float xb = lrelu(fmaf(acc1, inv, bb.y), NEG_ACT);

    // per-lane partial of h2[j] = sum_k x2[k]*W2[k][j]  (W2 rows 2*lane, 2*lane+1; L1-hot)
    float pj[16];
    {
        const float4* wra = (const float4*)(W2 + (size_t)(2 * lane) * 16);
        const float4* wrb = (const float4*)(W2 + (size_t)(2 * lane + 1) * 16);
        #pragma unroll
        for (int q = 0; q < 4; ++q) {
            float4 wa = wra[q], wb = wrb[q];
            pj[q * 4 + 0] = fmaf(xa, wa.x, xb * wb.x);
            pj[q * 4 + 1] = fmaf(xa, wa.y, xb * wb.y);
            pj[q * 4 + 2] = fmaf(xa, wa.z, xb * wb.z);
            pj[q * 4 + 3] = fmaf(xa, wa.w, xb * wb.w);
        }
    }
    #pragma unroll
    for (int m = 1; m < 64; m <<= 1) {
        #pragma unroll
        for (int q = 0; q < 16; ++q) pj[q] += __shfl_xor(pj[q], m, 64);
    }
    // all lanes now hold the full h2 row; attention dots are register-local
    float s_src = 0.f, s_dst = 0.f;
    #pragma unroll
    for (int q = 0; q < 4; ++q) {
        float4 av = ((const float4*)a2_src)[q];
        float4 dv = ((const float4*)a2_dst)[q];
        s_src += pj[q*4+0]*av.x + pj[q*4+1]*av.y + pj[q*4+2]*av.z + pj[q*4+3]*av.w;
        s_dst += pj[q*4+0]*dv.x + pj[q*4+1]*dv.y + pj[q*4+2]*dv.z + pj[q*4+3]*dv.w;
    }
    if (lane == 0) {
        float4* o = (float4*)(h2 + (size_t)d * 16);
        o[0] = make_float4(pj[0],  pj[1],  pj[2],  pj[3]);
        o[1] = make_float4(pj[4],  pj[5],  pj[6],  pj[7]);
        o[2] = make_float4(pj[8],  pj[9],  pj[10], pj[11]);
        o[3] = make_float4(pj[12], pj[13], pj[14], pj[15]);
        as2[d] = s_src;
        ad2[d] = s_dst;
    }
}

// ==================== K3: layer-2 gather + bias + final softmax (16 lanes/dst) ==========
__global__ __launch_bounds__(256) void k_agg2(
    const int* __restrict__ csr, const int* __restrict__ cursor, const int* __restrict__ counts,
    const float* __restrict__ as2, const float* __restrict__ ad2,
    const float* __restrict__ h2, const float* __restrict__ b2,
    float* __restrict__ out, int N)
{
    const int d = (blockIdx.x * 256 + threadIdx.x) >> 4;
    if (d >= N) return;
    const int j = threadIdx.x & 15;
    const int deg = counts[d];
    const int start = cursor[d] - deg;

    const float myad = ad2[d];
    float acc = 0.f, wsum = 0.f;
    for (int base = 0; base < deg; base += 16) {
        int cnt = min(deg - base, 16);
        int lidx = j < cnt ? j : cnt - 1;
        int sj = csr[start + base + lidx];
        int t = 0;
        for (; t + 4 <= cnt; t += 4) {
            int s0 = __shfl(sj, t, 16);
            int s1 = __shfl(sj, t + 1, 16);
            int s2 = __shfl(sj, t + 2, 16);
            int s3 = __shfl(sj, t + 3, 16);
            float e0 = as2[s0], e1 = as2[s1], e2 = as2[s2], e3 = as2[s3];
            float v0 = h2[(size_t)s0 * 16 + j];
            float v1 = h2[(size_t)s1 * 16 + j];
            float v2 = h2[(size_t)s2 * 16 + j];
            float v3 = h2[(size_t)s3 * 16 + j];
            float w0 = __expf(lrelu(e0 + myad, NEG_ATT));
            float w1 = __expf(lrelu(e1 + myad, NEG_ATT));
            float w2 = __expf(lrelu(e2 + myad, NEG_ATT));
            float w3 = __expf(lrelu(e3 + myad, NEG_ATT));
            acc = fmaf(w0, v0, acc); acc = fmaf(w1, v1, acc);
            acc = fmaf(w2, v2, acc); acc = fmaf(w3, v3, acc);
            wsum += w0 + w1 + w2 + w3;
        }
        for (; t < cnt; ++t) {
            int s = __shfl(sj, t, 16);
            float wgt = __expf(lrelu(as2[s] + myad, NEG_ATT));
            acc = fmaf(wgt, h2[(size_t)s * 16 + j], acc);
            wsum += wgt;
        }
    }
    float logit = acc / wsum + b2[j];
    float m = logit;
    #pragma unroll
    for (int s = 8; s >= 1; s >>= 1) m = fmaxf(m, __shfl_xor(m, s, 16));
    float ex = __expf(logit - m);
    float sum = ex;
    #pragma unroll
    for (int s = 8; s >= 1; s >>= 1) sum += __shfl_xor(sum, s, 16);
    out[(size_t)d * 16 + j] = ex / sum;
}

extern "C" void kernel_launch(void* const* d_in, const int* in_sizes, int n_in,
                              void* d_out, int out_size, void* d_ws, size_t ws_size,
                              hipStream_t stream)
{
    const float* x   = (const float*)d_in[0];
    const int*   ei  = (const int*)d_in[1];
    const float* W1  = (const float*)d_in[2];
    const float* a1s = (const float*)d_in[3];
    const float* a1d = (const float*)d_in[4];
    const float* b1  = (const float*)d_in[5];
    const float* W2  = (const float*)d_in[6];
    const float* a2s = (const float*)d_in[7];
    const float* a2d = (const float*)d_in[8];
    const float* b2  = (const float*)d_in[9];

    const int N = in_sizes[0] / 128;
    const int E = in_sizes[1] / 2;
    const int Etot = E + N;
    const int* srcp = ei;
    const int* dstp = ei + E;
    const int NB = (N + 1023) / 1024;   // blocks for the two-level scan

    // workspace layout (~73 MB)
    float* p = (float*)d_ws;
    float* h1  = p; p += (size_t)N * 128;
    float* as1 = p; p += (size_t)N * 8;
    float* ad1 = p; p += (size_t)N * 8;
    float* h2  = p; p += (size_t)N * 16;
    float* as2 = p; p += N;
    float* ad2 = p; p += N;
    int* counts = (int*)p; p += N;
    int* cursor = (int*)p; p += N;
    int* csr    = (int*)p; p += Etot;
    int* bsum   = (int*)p; p += 1024;
    int* boff   = (int*)p; p += 1024;

    hipMemsetAsync(counts, 0, (size_t)N * sizeof(int), stream);

    k_hist   <<<(Etot + 255) / 256, 256, 0, stream>>>(dstp, counts, E, Etot);
    k_bsum   <<<NB, 1024, 0, stream>>>(counts, bsum, N);
    k_scan   <<<1, 1024, 0, stream>>>(bsum, boff, NB);
    k_scanadd<<<NB, 1024, 0, stream>>>(counts, boff, cursor, N);
    k_scatter<<<(Etot + 255) / 256, 256, 0, stream>>>(srcp, dstp, cursor, csr, E, Etot);
    k_gemm1  <<<(N + 31) / 32, 256, 0, stream>>>(x, W1, a1s, a1d, h1, as1, ad1, N);
    k_agg1   <<<(N + 3) / 4, 256, 0, stream>>>(csr, cursor, counts, as1, ad1, h1, b1,
                                               W2, a2s, a2d, h2, as2, ad2, N);
    k_agg2   <<<(N * 16 + 255) / 256, 256, 0, stream>>>(csr, cursor, counts, as2, ad2, h2, b2,
                                                        (float*)d_out, N);
}

// Round 9
// 547.212 us; speedup vs baseline: 25.4694x; 1.0297x over previous
//
#include <hip/hip_runtime.h>
#include <hip/hip_bf16.h>
#include <math.h>

#define NEG_ATT 0.2f
#define NEG_ACT 0.01f

__device__ __forceinline__ float lrelu(float v, float s) { return v >= 0.f ? v : s * v; }

// round-to-nearest-even f32 -> bf16 (top 16 bits)
__device__ __forceinline__ unsigned int rne_bf16(float f) {
    unsigned int u = __float_as_uint(f);
    return (u + 0x7FFFu + ((u >> 16) & 1u)) >> 16;
}
// unpack u32 (2 bf16) -> 2 floats
__device__ __forceinline__ float2 bf2_to_f2(unsigned int v) {
    return make_float2(__uint_as_float(v << 16), __uint_as_float(v & 0xFFFF0000u));
}

// ==================== CSR build ====================
__global__ __launch_bounds__(256) void k_hist(
    const int* __restrict__ dst, int* __restrict__ counts, int E, int Etot)
{
    int e = blockIdx.x * 256 + threadIdx.x;
    if (e >= Etot) return;
    int d = (e < E) ? dst[e] : e - E;   // self-loops appended as edges [E, E+N)
    atomicAdd(&counts[d], 1);
}

__global__ __launch_bounds__(1024) void k_bsum(
    const int* __restrict__ counts, int* __restrict__ bsum, int N)
{
    int i = blockIdx.x * 1024 + threadIdx.x;
    int v = (i < N) ? counts[i] : 0;
    #pragma unroll
    for (int m = 1; m < 64; m <<= 1) v += __shfl_xor(v, m, 64);
    __shared__ int ws[16];
    int lane = threadIdx.x & 63, w = threadIdx.x >> 6;
    if (lane == 0) ws[w] = v;
    __syncthreads();
    if (threadIdx.x == 0) {
        int t = 0;
        #pragma unroll
        for (int k = 0; k < 16; ++k) t += ws[k];
        bsum[blockIdx.x] = t;
    }
}

__global__ __launch_bounds__(1024) void k_scan(
    const int* __restrict__ in, int* __restrict__ out, int N)
{
    __shared__ int wsum[16];
    __shared__ int carry_s;
    const int tid = threadIdx.x;
    const int lane = tid & 63, w = tid >> 6;
    if (tid == 0) carry_s = 0;
    __syncthreads();
    for (int base = 0; base < N; base += 1024) {
        int i = base + tid;
        int v = (i < N) ? in[i] : 0;
        int incl = v;
        #pragma unroll
        for (int s = 1; s < 64; s <<= 1) {
            int t = __shfl_up(incl, s, 64);
            if (lane >= s) incl += t;
        }
        if (lane == 63) wsum[w] = incl;
        __syncthreads();
        int woff = 0;
        #pragma unroll
        for (int k = 0; k < 16; ++k) woff += (k < w) ? wsum[k] : 0;
        int carry = carry_s;
        if (i < N) out[i] = carry + woff + incl - v;   // exclusive
        __syncthreads();
        if (tid == 1023) carry_s = carry + woff + incl;
        __syncthreads();
    }
}

__global__ __launch_bounds__(1024) void k_scanadd(
    const int* __restrict__ counts, const int* __restrict__ boff,
    int* __restrict__ cursor, int N)
{
    const int tid = threadIdx.x;
    const int i = blockIdx.x * 1024 + tid;
    int v = (i < N) ? counts[i] : 0;
    int incl = v;
    const int lane = tid & 63, w = tid >> 6;
    #pragma unroll
    for (int s = 1; s < 64; s <<= 1) {
        int t = __shfl_up(incl, s, 64);
        if (lane >= s) incl += t;
    }
    __shared__ int ws[16];
    if (lane == 63) ws[w] = incl;
    __syncthreads();
    int woff = 0;
    #pragma unroll
    for (int k = 0; k < 16; ++k) woff += (k < w) ? ws[k] : 0;
    if (i < N) cursor[i] = boff[blockIdx.x] + woff + incl - v;
}

__global__ __launch_bounds__(256) void k_scatter(
    const int* __restrict__ src, const int* __restrict__ dst,
    int* __restrict__ cursor, int* __restrict__ csr, int E, int Etot)
{
    int e = blockIdx.x * 256 + threadIdx.x;
    if (e >= Etot) return;
    int s, d;
    if (e < E) { s = src[e]; d = dst[e]; } else { s = e - E; d = s; }
    int pos = atomicAdd(&cursor[d], 1);
    csr[pos] = s;
}

// ==================== K1: h1 = x @ W1 (+ attention dots); h1 stored bf16 ====================
__global__ __launch_bounds__(256) void k_gemm1(
    const float* __restrict__ x, const float* __restrict__ W,
    const float* __restrict__ a_src, const float* __restrict__ a_dst,
    unsigned int* __restrict__ h1b, float* __restrict__ as1, float* __restrict__ ad1, int N)
{
    __shared__ float Wl[128 * 128];
    const int tid = threadIdx.x;
    {
        float4* Wl4 = (float4*)Wl;
        const float4* W4 = (const float4*)W;
        #pragma unroll
        for (int i = 0; i < 16; ++i) Wl4[tid + i * 256] = W4[tid + i * 256];
    }
    __syncthreads();

    const int nl = tid & 31, hg = tid >> 5;
    int n = blockIdx.x * 32 + nl;
    if (n >= N) n = N - 1;

    const float4* xrow = (const float4*)(x + (size_t)n * 128);
    float acc[16];
    #pragma unroll
    for (int j = 0; j < 16; ++j) acc[j] = 0.f;

    for (int k4 = 0; k4 < 32; ++k4) {
        float4 xv4 = xrow[k4];
        float xs[4] = {xv4.x, xv4.y, xv4.z, xv4.w};
        #pragma unroll
        for (int kk = 0; kk < 4; ++kk) {
            const float4* wr = (const float4*)(Wl + (k4 * 4 + kk) * 128 + hg * 16);
            float4 w0 = wr[0], w1 = wr[1], w2 = wr[2], w3 = wr[3];
            float xv = xs[kk];
            acc[0]  = fmaf(xv, w0.x, acc[0]);  acc[1]  = fmaf(xv, w0.y, acc[1]);
            acc[2]  = fmaf(xv, w0.z, acc[2]);  acc[3]  = fmaf(xv, w0.w, acc[3]);
            acc[4]  = fmaf(xv, w1.x, acc[4]);  acc[5]  = fmaf(xv, w1.y, acc[5]);
            acc[6]  = fmaf(xv, w1.z, acc[6]);  acc[7]  = fmaf(xv, w1.w, acc[7]);
            acc[8]  = fmaf(xv, w2.x, acc[8]);  acc[9]  = fmaf(xv, w2.y, acc[9]);
            acc[10] = fmaf(xv, w2.z, acc[10]); acc[11] = fmaf(xv, w2.w, acc[11]);
            acc[12] = fmaf(xv, w3.x, acc[12]); acc[13] = fmaf(xv, w3.y, acc[13]);
            acc[14] = fmaf(xv, w3.z, acc[14]); acc[15] = fmaf(xv, w3.w, acc[15]);
        }
    }

    float s_src = 0.f, s_dst = 0.f;
    const float* av = a_src + hg * 16;
    const float* bv = a_dst + hg * 16;
    #pragma unroll
    for (int j = 0; j < 16; ++j) {
        s_src = fmaf(acc[j], av[j], s_src);
        s_dst = fmaf(acc[j], bv[j], s_dst);
    }

    unsigned int pk[8];
    #pragma unroll
    for (int q = 0; q < 8; ++q) {
        unsigned int lo = rne_bf16(acc[2 * q]);
        unsigned int u  = __float_as_uint(acc[2 * q + 1]);
        unsigned int hi = (u + 0x7FFFu + ((u >> 16) & 1u)) & 0xFFFF0000u;
        pk[q] = lo | hi;
    }
    uint4* o = (uint4*)(h1b + (size_t)n * 64 + hg * 8);
    o[0] = make_uint4(pk[0], pk[1], pk[2], pk[3]);
    o[1] = make_uint4(pk[4], pk[5], pk[6], pk[7]);
    as1[n * 8 + hg] = s_src;
    ad1[n * 8 + hg] = s_dst;
}

// ==================== K2: layer-1 gather + fused layer-2 transform ====================
// One wave per dst; h1 gathered as bf16 pairs (256 B/row, half of round-6 traffic).
// Epilogue packs h2(bf16)+as2 into one 64-B rec2 line per node.
__global__ __launch_bounds__(256) void k_agg1(
    const int* __restrict__ csr, const int* __restrict__ cursor, const int* __restrict__ counts,
    const float* __restrict__ as1, const float* __restrict__ ad1,
    const unsigned int* __restrict__ h1b, const float* __restrict__ b1,
    const float* __restrict__ W2, const float* __restrict__ a2_src, const float* __restrict__ a2_dst,
    unsigned int* __restrict__ rec2, float* __restrict__ ad2, int N)
{
    const int d = (blockIdx.x * 256 + threadIdx.x) >> 6;   // one wave per destination
    if (d >= N) return;                                     // wave-uniform; no barriers below
    const int lane = threadIdx.x & 63;
    const int h = lane >> 3;
    const int deg = counts[d];
    const int start = cursor[d] - deg;   // cursor holds segment END after k_scatter

    const float myad = ad1[d * 8 + h];
    float acc0 = 0.f, acc1 = 0.f, wsum = 0.f;

    for (int base = 0; base < deg; base += 64) {
        int cnt = min(deg - base, 64);
        int lidx = lane < cnt ? lane : cnt - 1;
        int sj = csr[start + base + lidx];
        int j = 0;
        for (; j + 4 <= cnt; j += 4) {
            int s0 = __shfl(sj, j);
            int s1 = __shfl(sj, j + 1);
            int s2 = __shfl(sj, j + 2);
            int s3 = __shfl(sj, j + 3);
            float e0 = as1[s0 * 8 + h], e1 = as1[s1 * 8 + h];
            float e2 = as1[s2 * 8 + h], e3 = as1[s3 * 8 + h];
            unsigned int u0 = h1b[(size_t)s0 * 64 + lane];
            unsigned int u1 = h1b[(size_t)s1 * 64 + lane];
            unsigned int u2 = h1b[(size_t)s2 * 64 + lane];
            unsigned int u3 = h1b[(size_t)s3 * 64 + lane];
            float w0 = __expf(lrelu(e0 + myad, NEG_ATT));
            float w1 = __expf(lrelu(e1 + myad, NEG_ATT));
            float w2 = __expf(lrelu(e2 + myad, NEG_ATT));
            float w3 = __expf(lrelu(e3 + myad, NEG_ATT));
            float2 v0 = bf2_to_f2(u0), v1 = bf2_to_f2(u1);
            float2 v2 = bf2_to_f2(u2), v3 = bf2_to_f2(u3);
            acc0 = fmaf(w0, v0.x, acc0); acc1 = fmaf(w0, v0.y, acc1);
            acc0 = fmaf(w1, v1.x, acc0); acc1 = fmaf(w1, v1.y, acc1);
            acc0 = fmaf(w2, v2.x, acc0); acc1 = fmaf(w2, v2.y, acc1);
            acc0 = fmaf(w3, v3.x, acc0); acc1 = fmaf(w3, v3.y, acc1);
            wsum += w0 + w1 + w2 + w3;
        }
        for (; j < cnt; ++j) {
            int s = __shfl(sj, j);
            float wgt = __expf(lrelu(as1[s * 8 + h] + myad, NEG_ATT));
            float2 hv = bf2_to_f2(h1b[(size_t)s * 64 + lane]);
            acc0 = fmaf(wgt, hv.x, acc0);
            acc1 = fmaf(wgt, hv.y, acc1);
            wsum += wgt;
        }
    }

    // x2 row elements owned by this lane (channels 2*lane, 2*lane+1)
    float inv = 1.f / wsum;
    float2 bb = *(const float2*)(b1 + lane * 2);
    float xa = lrelu(fmaf(acc0, inv, bb.x), NEG_ACT);
    float xb = lrelu(fmaf(acc1, inv, bb.y), NEG_ACT);

    // per-lane partial of h2[j] = sum_k x2[k]*W2[k][j]
    float pj[16];
    {
        const float4* wra = (const float4*)(W2 + (size_t)(2 * lane) * 16);
        const float4* wrb = (const float4*)(W2 + (size_t)(2 * lane + 1) * 16);
        #pragma unroll
        for (int q = 0; q < 4; ++q) {
            float4 wa = wra[q], wb = wrb[q];
            pj[q * 4 + 0] = fmaf(xa, wa.x, xb * wb.x);
            pj[q * 4 + 1] = fmaf(xa, wa.y, xb * wb.y);
            pj[q * 4 + 2] = fmaf(xa, wa.z, xb * wb.z);
            pj[q * 4 + 3] = fmaf(xa, wa.w, xb * wb.w);
        }
    }
    #pragma unroll
    for (int m = 1; m < 64; m <<= 1) {
        #pragma unroll
        for (int q = 0; q < 16; ++q) pj[q] += __shfl_xor(pj[q], m, 64);
    }
    float s_src = 0.f, s_dst = 0.f;
    #pragma unroll
    for (int q = 0; q < 4; ++q) {
        float4 av = ((const float4*)a2_src)[q];
        float4 dv = ((const float4*)a2_dst)[q];
        s_src += pj[q*4+0]*av.x + pj[q*4+1]*av.y + pj[q*4+2]*av.z + pj[q*4+3]*av.w;
        s_dst += pj[q*4+0]*dv.x + pj[q*4+1]*dv.y + pj[q*4+2]*dv.z + pj[q*4+3]*dv.w;
    }
    if (lane == 0) {
        // rec2[d]: 64-B record = h2 bf16[16] (32 B) | as2 f32 (4 B) | pad
        unsigned int pk[8];
        #pragma unroll
        for (int q = 0; q < 8; ++q) {
            unsigned int lo = rne_bf16(pj[2 * q]);
            unsigned int u  = __float_as_uint(pj[2 * q + 1]);
            unsigned int hi = (u + 0x7FFFu + ((u >> 16) & 1u)) & 0xFFFF0000u;
            pk[q] = lo | hi;
        }
        uint4* o = (uint4*)(rec2 + (size_t)d * 16);
        o[0] = make_uint4(pk[0], pk[1], pk[2], pk[3]);
        o[1] = make_uint4(pk[4], pk[5], pk[6], pk[7]);
        rec2[(size_t)d * 16 + 8] = __float_as_uint(s_src);
        ad2[d] = s_dst;
    }
}

// ==================== K3: layer-2 gather + bias + final softmax (16 lanes/dst) ==========
// Per edge: ONE 64-B line (rec2[s] holds h2 bf16 + as2).
__global__ __launch_bounds__(256) void k_agg2(
    const int* __restrict__ csr, const int* __restrict__ cursor, const int* __restrict__ counts,
    const unsigned int* __restrict__ rec2, const float* __restrict__ ad2,
    const float* __restrict__ b2, float* __restrict__ out, int N)
{
    const int d = (blockIdx.x * 256 + threadIdx.x) >> 4;
    if (d >= N) return;
    const int j = threadIdx.x & 15;
    const int deg = counts[d];
    const int start = cursor[d] - deg;

    const float myad = ad2[d];
    float acc = 0.f, wsum = 0.f;
    for (int base = 0; base < deg; base += 16) {
        int cnt = min(deg - base, 16);
        int lidx = j < cnt ? j : cnt - 1;
        int sj = csr[start + base + lidx];
        int t = 0;
        for (; t + 4 <= cnt; t += 4) {
            int s0 = __shfl(sj, t, 16);
            int s1 = __shfl(sj, t + 1, 16);
            int s2 = __shfl(sj, t + 2, 16);
            int s3 = __shfl(sj, t + 3, 16);
            const unsigned int* r0 = rec2 + (size_t)s0 * 16;
            const unsigned int* r1 = rec2 + (size_t)s1 * 16;
            const unsigned int* r2 = rec2 + (size_t)s2 * 16;
            const unsigned int* r3 = rec2 + (size_t)s3 * 16;
            unsigned int p0 = r0[j >> 1], p1 = r1[j >> 1], p2 = r2[j >> 1], p3 = r3[j >> 1];
            float e0 = __uint_as_float(r0[8]), e1 = __uint_as_float(r1[8]);
            float e2 = __uint_as_float(r2[8]), e3 = __uint_as_float(r3[8]);
            float v0 = __uint_as_float((j & 1) ? (p0 & 0xFFFF0000u) : (p0 << 16));
            float v1 = __uint_as_float((j & 1) ? (p1 & 0xFFFF0000u) : (p1 << 16));
            float v2 = __uint_as_float((j & 1) ? (p2 & 0xFFFF0000u) : (p2 << 16));
            float v3 = __uint_as_float((j & 1) ? (p3 & 0xFFFF0000u) : (p3 << 16));
            float w0 = __expf(lrelu(e0 + myad, NEG_ATT));
            float w1 = __expf(lrelu(e1 + myad, NEG_ATT));
            float w2 = __expf(lrelu(e2 + myad, NEG_ATT));
            float w3 = __expf(lrelu(e3 + myad, NEG_ATT));
            acc = fmaf(w0, v0, acc); acc = fmaf(w1, v1, acc);
            acc = fmaf(w2, v2, acc); acc = fmaf(w3, v3, acc);
            wsum += w0 + w1 + w2 + w3;
        }
        for (; t < cnt; ++t) {
            int s = __shfl(sj, t, 16);
            const unsigned int* r = rec2 + (size_t)s * 16;
            unsigned int p = r[j >> 1];
            float v = __uint_as_float((j & 1) ? (p & 0xFFFF0000u) : (p << 16));
            float wgt = __expf(lrelu(__uint_as_float(r[8]) + myad, NEG_ATT));
            acc = fmaf(wgt, v, acc);
            wsum += wgt;
        }
    }
    float logit = acc / wsum + b2[j];
    float m = logit;
    #pragma unroll
    for (int s = 8; s >= 1; s >>= 1) m = fmaxf(m, __shfl_xor(m, s, 16));
    float ex = __expf(logit - m);
    float sum = ex;
    #pragma unroll
    for (int s = 8; s >= 1; s >>= 1) sum += __shfl_xor(sum, s, 16);
    out[(size_t)d * 16 + j] = ex / sum;
}

extern "C" void kernel_launch(void* const* d_in, const int* in_sizes, int n_in,
                              void* d_out, int out_size, void* d_ws, size_t ws_size,
                              hipStream_t stream)
{
    const float* x   = (const float*)d_in[0];
    const int*   ei  = (const int*)d_in[1];
    const float* W1  = (const float*)d_in[2];
    const float* a1s = (const float*)d_in[3];
    const float* a1d = (const float*)d_in[4];
    const float* b1  = (const float*)d_in[5];
    const float* W2  = (const float*)d_in[6];
    const float* a2s = (const float*)d_in[7];
    const float* a2d = (const float*)d_in[8];
    const float* b2  = (const float*)d_in[9];

    const int N = in_sizes[0] / 128;
    const int E = in_sizes[1] / 2;
    const int Etot = E + N;
    const int* srcp = ei;
    const int* dstp = ei + E;
    const int NB = (N + 1023) / 1024;

    // workspace layout (~47 MB)
    float* p = (float*)d_ws;
    unsigned int* h1b = (unsigned int*)p; p += (size_t)N * 64;   // bf16-packed h1
    float* as1 = p; p += (size_t)N * 8;
    float* ad1 = p; p += (size_t)N * 8;
    unsigned int* rec2 = (unsigned int*)p; p += (size_t)N * 16;  // h2(bf16)+as2 records
    float* ad2 = p; p += N;
    int* counts = (int*)p; p += N;
    int* cursor = (int*)p; p += N;
    int* csr    = (int*)p; p += Etot;
    int* bsum   = (int*)p; p += 1024;
    int* boff   = (int*)p; p += 1024;

    hipMemsetAsync(counts, 0, (size_t)N * sizeof(int), stream);

    k_hist   <<<(Etot + 255) / 256, 256, 0, stream>>>(dstp, counts, E, Etot);
    k_bsum   <<<NB, 1024, 0, stream>>>(counts, bsum, N);
    k_scan   <<<1, 1024, 0, stream>>>(bsum, boff, NB);
    k_scanadd<<<NB, 1024, 0, stream>>>(counts, boff, cursor, N);
    k_scatter<<<(Etot + 255) / 256, 256, 0, stream>>>(srcp, dstp, cursor, csr, E, Etot);
    k_gemm1  <<<(N + 31) / 32, 256, 0, stream>>>(x, W1, a1s, a1d, h1b, as1, ad1, N);
    k_agg1   <<<(N + 3) / 4, 256, 0, stream>>>(csr, cursor, counts, as1, ad1, h1b, b1,
                                               W2, a2s, a2d, rec2, ad2, N);
    k_agg2   <<<(N * 16 + 255) / 256, 256, 0, stream>>>(csr, cursor, counts, rec2, ad2, b2,
                                                        (float*)d_out, N);
}